// Round 4
// baseline (1783.833 us; speedup 1.0000x reference)
//
#include <hip/hip_runtime.h>
#include <stdint.h>

// Problem constants (B,T,H,V) = (4,1024,2048,32000)
#define M_TOK 4096
#define N_VOC 32000
#define K_DIM 2048
#define BM 256
#define BN 256
#define BK 64
#define NT (K_DIM / BK)  // 32 K-tiles
#define BETA 0.1f
#define W_SCALE 32.0f
#define INV_W_SCALE (1.0f / 32.0f)

typedef float f32x4 __attribute__((ext_vector_type(4)));

// fp32 -> fp8 e4m3 (OCP) cast with static scale.
// 16 B/lane fully-coalesced read (float4), 4 B/lane packed write.
__global__ __launch_bounds__(256) void cast_f32_fp8(const float* __restrict__ in,
                                                    unsigned* __restrict__ out, int n4,
                                                    float scale) {
  int i = blockIdx.x * blockDim.x + threadIdx.x;
  int stride = gridDim.x * blockDim.x;
  const float4* __restrict__ in4 = (const float4*)in;
  for (; i < n4; i += stride) {
    float4 f = in4[i];
    int v = __builtin_amdgcn_cvt_pk_fp8_f32(f.x * scale, f.y * scale, 0, false);
    v = __builtin_amdgcn_cvt_pk_fp8_f32(f.z * scale, f.w * scale, v, true);
    out[i] = (unsigned)v;
  }
}

// C = A(M,K) @ B(N,K)^T in fp8 e4m3 (B pre-scaled by W_SCALE), reduced over N:
//   S[m] += sum_n exp(C[m,n]);  L[m] += sum_n C[m,n];  sel[m] = C[m, ids[m]]
//
// 256x256 tile, 8 waves (2M x 4N), TRUE counted-vmcnt deep pipeline (T3+T4):
// 3 LDS buffers x 32KB (A 16KB | B 16KB each) = 96KB. While computing tile t
// (buffer t%3) we stage tile t+2 (buffer (t+2)%3); at each tile boundary the
// per-wave outstanding loads are 8 (tiles t, t+1) and s_waitcnt vmcnt(4)
// retires exactly tile t's 4 -- 4 loads stay in flight across every barrier.
// Each K-tile = 4 fine phases (ks x ih quadrants, 16 MFMA each):
//   {ds_read subtile || 1 global_load_lds} -> s_barrier -> sched_barrier(0)
//   -> setprio(1) + 16 MFMA + setprio(0) -> s_barrier
// Rows are 64B = 4 x 16B chunks, chunk c of row r stored at c ^ swz(r mod 16),
// swz(r) = (r&3)^((r>>2)&3); applied on the pre-swizzled global SOURCE
// (global_load_lds dest linear) and on the ds_read address (rule #21).
__global__ __launch_bounds__(512, 2) void gemm_stats(
    const unsigned char* __restrict__ A,   // [M_TOK][K_DIM] fp8
    const unsigned char* __restrict__ B,   // [N_VOC][K_DIM] fp8 (scaled by W_SCALE)
    const int* __restrict__ ids,           // [M_TOK]
    float* __restrict__ S, float* __restrict__ L, float* __restrict__ sel) {
  __shared__ unsigned char lds[3 * 32768];  // [buf:3][A 16KB | B 16KB]

  const int tid = threadIdx.x;
  const int w = tid >> 6;     // wave 0..7
  const int l = tid & 63;
  const int m0 = blockIdx.y * BM;
  const int n0 = blockIdx.x * BN;
  const int wm = w >> 2, wn = w & 3;  // 2x4 wave grid; per-wave out = 128x64
  const int l15 = l & 15, quad = l >> 4;

  // Staging: for half h (rows h*128..h*128+127), wave w loads 16 rows
  // (h*128 + w*16 + srow), 4 lanes/row, 16B each = 1KB per GLL call.
  const int srow = l >> 2;                                   // 0..15
  const int sc = (l & 3) ^ (srow & 3) ^ ((srow >> 2) & 3);   // logical 16B chunk
  const unsigned char* pA = A + (size_t)(m0 + w * 16 + srow) * K_DIM + sc * 16;
  const unsigned char* pB = B + (size_t)(n0 + w * 16 + srow) * K_DIM + sc * 16;
  const size_t HS = (size_t)128 * K_DIM;  // half-tile row stride in global

  unsigned char* dA = &lds[w * 1024];            // + b*32768 + h*8192
  unsigned char* dB = &lds[16384 + w * 1024];    // + b*32768 + h*8192

  // Fragment read offsets. A-frag (i,ks): row wm*128 + i*16 + l15, logical
  // chunk ks*2 + (quad>>1), phys = chunk ^ swz(l15), sub-off (quad&1)*8.
  // ks toggles byte-bit5 of the chunk part -> XOR with (ks<<5).
  const int sw = (l15 & 3) ^ ((l15 >> 2) & 3);
  const int aoffBase = wm * 8192 + l15 * 64 + (((quad >> 1) ^ sw) << 4) + (quad & 1) * 8;
  const int boffBase = 16384 + wn * 4096 + l15 * 64 + (((quad >> 1) ^ sw) << 4) + (quad & 1) * 8;

  f32x4 acc[8][4];
  const f32x4 zero = {0.f, 0.f, 0.f, 0.f};
#pragma unroll
  for (int i = 0; i < 8; ++i)
#pragma unroll
    for (int j = 0; j < 4; ++j) acc[i][j] = zero;

#define GLL(src, dst)                                                              \
  __builtin_amdgcn_global_load_lds(                                                \
      (const __attribute__((address_space(1))) unsigned int*)(src),                \
      (__attribute__((address_space(3))) unsigned int*)(dst), 16, 0, 0)

#define STAGE_A_H(b, h, kn) GLL(pA + HS * (h) + (kn), dA + (b) * 32768 + (h) * 8192)
#define STAGE_B_H(b, h, kn) GLL(pB + HS * (h) + (kn), dB + (b) * 32768 + (h) * 8192)

#define LOAD_B(rd, ks)                                                             \
  _Pragma("unroll") for (int j = 0; j < 4; ++j)                                    \
      bq[j] = *(const long long*)(&lds[(rd) * 32768] +                             \
                                  ((boffBase ^ ((ks) << 5)) + j * 1024));

#define LOAD_A(rd, ks, ih)                                                         \
  _Pragma("unroll") for (int i = 0; i < 4; ++i)                                    \
      af[i] = *(const long long*)(&lds[(rd) * 32768] +                             \
                                  ((aoffBase ^ ((ks) << 5)) + ((ih) * 4 + i) * 1024));

#define MFMA16(ih)                                                                 \
  do {                                                                             \
    __builtin_amdgcn_s_setprio(1);                                                 \
    _Pragma("unroll") for (int i = 0; i < 4; ++i)                                  \
      _Pragma("unroll") for (int j = 0; j < 4; ++j)                                \
        acc[(ih) * 4 + i][j] = __builtin_amdgcn_mfma_f32_16x16x32_fp8_fp8(         \
            af[i], bq[j], acc[(ih) * 4 + i][j], 0, 0, 0);                          \
    __builtin_amdgcn_s_setprio(0);                                                 \
  } while (0)

#define PRE_MFMA_BAR()                                                             \
  do {                                                                             \
    __builtin_amdgcn_s_barrier();                                                  \
    __builtin_amdgcn_sched_barrier(0);                                             \
  } while (0)

#define TILE_CORE(rd, S0, S1, S2, S3, VWAIT)                                       \
  do {                                                                             \
    asm volatile("s_waitcnt vmcnt(" VWAIT ")" ::: "memory");                       \
    __builtin_amdgcn_s_barrier();                                                  \
    long long af[4], bq[4];                                                        \
    LOAD_B(rd, 0); LOAD_A(rd, 0, 0); S0;                                           \
    PRE_MFMA_BAR(); MFMA16(0); __builtin_amdgcn_s_barrier();                       \
    LOAD_A(rd, 0, 1); S1;                                                          \
    PRE_MFMA_BAR(); MFMA16(1); __builtin_amdgcn_s_barrier();                       \
    LOAD_B(rd, 1); LOAD_A(rd, 1, 0); S2;                                           \
    PRE_MFMA_BAR(); MFMA16(0); __builtin_amdgcn_s_barrier();                       \
    LOAD_A(rd, 1, 1); S3;                                                          \
    PRE_MFMA_BAR(); MFMA16(1); __builtin_amdgcn_s_barrier();                       \
  } while (0)

#define TILE_S(rd, w2, kn2)                                                        \
  TILE_CORE(rd, STAGE_A_H(w2, 0, kn2), STAGE_B_H(w2, 0, kn2),                      \
            STAGE_A_H(w2, 1, kn2), STAGE_B_H(w2, 1, kn2), "4")
#define TILE_N(rd, VW) TILE_CORE(rd, (void)0, (void)0, (void)0, (void)0, VW)

  // Prologue: stage tile 0 -> buf0, tile 1 -> buf1 (8 loads in flight/wave).
  STAGE_A_H(0, 0, 0); STAGE_B_H(0, 0, 0); STAGE_A_H(0, 1, 0); STAGE_B_H(0, 1, 0);
  STAGE_A_H(1, 0, BK); STAGE_B_H(1, 0, BK); STAGE_A_H(1, 1, BK); STAGE_B_H(1, 1, BK);

  // Steady state: 30 staged tiles, unrolled x3 for compile-time buffer indices.
  for (int tb = 0; tb < NT - 2; tb += 3) {
    TILE_S(0, 2, (tb + 2) * BK);  // compute tile tb,   stage tile tb+2 -> buf2
    TILE_S(1, 0, (tb + 3) * BK);  // compute tile tb+1, stage tile tb+3 -> buf0
    TILE_S(2, 1, (tb + 4) * BK);  // compute tile tb+2, stage tile tb+4 -> buf1
  }
  // Tail: tiles 30 (buf0) and 31 (buf1); drain 4 -> 0.
  TILE_N(0, "4");
  TILE_N(1, "0");

#undef GLL
#undef STAGE_A_H
#undef STAGE_B_H
#undef LOAD_A
#undef LOAD_B
#undef MFMA16
#undef PRE_MFMA_BAR
#undef TILE_CORE
#undef TILE_S
#undef TILE_N

  // Epilogue. C/D layout (m89/m121): col = lane&15, row = quad*4 + reg.
  // Lane owns rows {wm*128 + i*16 + quad*4 + r}, cols {n0 + wn*64 + j*16 + l15}.
  // Logits were computed against W*W_SCALE -> multiply by INV_W_SCALE.
#pragma unroll
  for (int i = 0; i < 8; ++i) {
#pragma unroll
    for (int r = 0; r < 4; ++r) {
      int row = m0 + wm * 128 + i * 16 + quad * 4 + r;
      int sid = ids[row];
      int loc = sid - n0 - wn * 64;
      bool hit = (loc >= 0) && (loc < 64) && ((loc & 15) == l15);
      float es = 0.f, ls = 0.f, selv = 0.f;
#pragma unroll
      for (int j = 0; j < 4; ++j) {
        float v = acc[i][j][r] * INV_W_SCALE;
        es += __expf(v);
        ls += v;
        if (hit && ((loc >> 4) == j)) selv = v;
      }
      if (hit) sel[row] = selv;  // unique writer across grid
      // butterfly across the quad's 16 lanes (masks < 16 stay in-group)
#pragma unroll
      for (int mk = 1; mk < 16; mk <<= 1) {
        es += __shfl_xor(es, mk);
        ls += __shfl_xor(ls, mk);
      }
      if (l15 == 0) {
        atomicAdd(&S[row], es);
        atomicAdd(&L[row], ls);
      }
    }
  }
}

__global__ __launch_bounds__(1024) void finalize_kernel(
    const float* __restrict__ S1, const float* __restrict__ L1, const float* __restrict__ P1,
    const float* __restrict__ S2, const float* __restrict__ P2,
    const float* __restrict__ mask, const float* __restrict__ adv, float* __restrict__ out) {
  __shared__ float red[12];
  int tid = threadIdx.x;
  int lane = tid & 63;
  if (tid < 12) red[tid] = 0.f;
  __syncthreads();

  float loss_num = 0.f, mask_sum = 0.f, ptl_sum = 0.f, lpm_sum = 0.f;
  float klb[4] = {0.f, 0.f, 0.f, 0.f}, mb[4] = {0.f, 0.f, 0.f, 0.f};
#pragma unroll
  for (int k = 0; k < 4; ++k) {
    int t = k * 1024 + tid;  // batch index b == k exactly
    float lse1 = logf(S1[t]);
    float ptl = P1[t] - lse1;
    float ref_ptl = P2[t] - logf(S2[t]);
    float d = ref_ptl - ptl;
    float kl = expf(d) - d - 1.f;
    float m = mask[t];
    float a = adv[k];
    // coef_1 = exp(ptl - stopgrad(ptl)) = 1; coef_2 = clip(1,...) = 1
    // per_token_loss = -min(adv, adv) + BETA*kl = -adv + BETA*kl
    loss_num += (-a + BETA * kl) * m;
    mask_sum += m;
    ptl_sum += ptl;
    lpm_sum += L1[t] * (1.f / (float)N_VOC) - lse1;
    klb[k] += kl * m;
    mb[k] += m;
  }
  float vals[12] = {loss_num, mask_sum, ptl_sum, lpm_sum,
                    klb[0], klb[1], klb[2], klb[3],
                    mb[0],  mb[1],  mb[2],  mb[3]};
#pragma unroll
  for (int v = 0; v < 12; ++v) {
    float xv = vals[v];
#pragma unroll
    for (int mk = 32; mk >= 1; mk >>= 1) xv += __shfl_xor(xv, mk);
    if (lane == 0) atomicAdd(&red[v], xv);
  }
  __syncthreads();
  if (tid == 0) {
    float loss = red[0] / fmaxf(red[1], 1.f);
    float km = 0.f;
#pragma unroll
    for (int b = 0; b < 4; ++b) km += red[4 + b] / fmaxf(red[8 + b], 1.f);
    out[0] = loss;                       // loss
    out[1] = red[2] * (1.f / 4096.f);    // per_token_logps.mean()
    out[2] = red[3] * (1.f / 4096.f);    // log_probs.mean()
    out[3] = km * 0.25f;                 // kl_metric
  }
}

extern "C" void kernel_launch(void* const* d_in, const int* in_sizes, int n_in,
                              void* d_out, int out_size, void* d_ws, size_t ws_size,
                              hipStream_t stream) {
  const float* x = (const float*)d_in[0];
  const float* W = (const float*)d_in[1];
  const float* ref_W = (const float*)d_in[2];
  const float* ref_x = (const float*)d_in[3];
  const int* ids = (const int*)d_in[4];
  const float* mask = (const float*)d_in[5];
  const float* adv = (const float*)d_in[6];
  float* out = (float*)d_out;

  // Workspace layout: [ Wq8 65.5MB | xq8 8.4MB | accum 96KB ]  (~74MB)
  char* ws = (char*)d_ws;
  unsigned char* Wq = (unsigned char*)ws;
  unsigned char* xq = (unsigned char*)(ws + (size_t)N_VOC * K_DIM);
  float* accum = (float*)(ws + (size_t)N_VOC * K_DIM + (size_t)M_TOK * K_DIM);
  float* S1 = accum;
  float* L1 = accum + 4096;
  float* P1 = accum + 8192;
  float* S2 = accum + 12288;
  float* L2 = accum + 16384;
  float* P2 = accum + 20480;

  hipMemsetAsync(accum, 0, 6 * 4096 * sizeof(float), stream);

  dim3 grid(N_VOC / BN, M_TOK / BM);  // 125 x 16

  cast_f32_fp8<<<2048, 256, 0, stream>>>(W, (unsigned*)Wq, N_VOC * K_DIM / 4, W_SCALE);
  cast_f32_fp8<<<512, 256, 0, stream>>>(x, (unsigned*)xq, M_TOK * K_DIM / 4, 1.0f);
  gemm_stats<<<grid, 512, 0, stream>>>(xq, Wq, ids, S1, L1, P1);

  // W buffer reused for ref (stream-ordered after gemm 1)
  cast_f32_fp8<<<2048, 256, 0, stream>>>(ref_W, (unsigned*)Wq, N_VOC * K_DIM / 4, W_SCALE);
  cast_f32_fp8<<<512, 256, 0, stream>>>(ref_x, (unsigned*)xq, M_TOK * K_DIM / 4, 1.0f);
  gemm_stats<<<grid, 512, 0, stream>>>(xq, Wq, ids, S2, L2, P2);

  finalize_kernel<<<1, 1024, 0, stream>>>(S1, L1, P1, S2, P2, mask, adv, out);
}